// Round 11
// baseline (168.142 us; speedup 1.0000x reference)
//
#include <hip/hip_runtime.h>

// GMELoss3D: fused 3D Sobel edge-magnitude MSE on [2,2,128,128,128] fp32 volumes.
// R13: break the 128-VGPR cliff — r-history factorization + launch_bounds(256,4).
//   - R12 post-mortem: kernel ~32us, 4.2cy/output vs ~2.0cy issue floor at the
//     VGPR-imposed 2 waves/SIMD (~180 regs > 128 cliff). Occupancy doubling
//     requires <=128 VGPR; R12's combo pipeline K (7 combos x 2 planes x
//     2 vols = 84 floats) + ring (72) makes that impossible.
//   - Fix: stencil ops COMMUTE (x/y/z separable). Store only per-row
//     channel-sums r (3 rows x 2 vols = 6 v2f/plane) in a mod-3 z-history
//     (36 floats, not 84); full z->y->x combine at emit (+~40% VALU/output,
//     paid for by 2x occupancy). Ring-2 raw (48 floats) keeps 2-iteration
//     vmcnt cover: iter j sums plane j (issued j-2), reuses the slot for
//     plane j+2, emits output j-1 from R[(j-2..j)%3].
//   - __launch_bounds__(256,4): cap 128 VGPR -> 4 waves/SIMD. Calculated
//     risk vs R3 (that clamp was 52->32; this is ~135->128, marginal remat).
//     ABORT TRIPWIRE: WRITE_SIZE in MBs = spilled -> revert next round.
//   - ZC 16->8: 1024 blocks = 4/CU supply for the 16 waves/CU target.
//   - Full #pragma unroll (10 iters): unroll-by-6 on trip-10 leaves a runtime
//     remainder -> dynamic R/pf indexing -> scratch (rule #20).
//   - Kept from R8..R12: branchless clamped loads, consume-time value masks,
//     full-row waves with dwordx2, seam bperms, v_sqrt_f32, no __syncthreads
//     in the z-loop.
//
// Decomposition: s=[1,2,1], d=[-1,0,1], e=[1,1,1] applied z-first at emit:
//   per row: zs,zd,ze; y-combine to 7 (z,y) pairs ss,sd,ds,se,de,ed,es;
//   x-combine: g1=dx(ss) g2=sx(sd) g3=sx(ds) g4/5=dx(se)∓ex(sd)
//   g6/7=sx(de)∓sx(ed) g8/9=dx(es)∓ex(ds). Signs irrelevant (squared).

namespace {

typedef float v2f __attribute__((ext_vector_type(2)));

constexpr int ZDIM = 128, YDIM = 128, XDIM = 128;   // (H, W, D); D contiguous
constexpr int TX = 64, TY = 4, ZC = 8;
constexpr int XW  = XDIM / 2;             // 64 float2 per row (lane i: x=2i,2i+1)
constexpr int YX2 = YDIM * XW;            // float2 per z-plane
constexpr size_t CS2 = (size_t)ZDIM * YX2;  // channel stride in float2
constexpr float INV_N = 1.0f / 4194304.0f;

__device__ __forceinline__ float bperm(int addr, float v) {
  return __int_as_float(__builtin_amdgcn_ds_bpermute(addr, __float_as_int(v)));
}

__device__ __forceinline__ v2f vfma(v2f a, v2f b, v2f c) {
  return __builtin_elementwise_fma(a, b, c);
}

__device__ __forceinline__ v2f vsplat(float x) { v2f r = {x, x}; return r; }

__global__ __launch_bounds__(256, 4)   // cap 128 VGPR -> 4 waves/SIMD
void gme_loss_kernel(const float* __restrict__ y,
                     const float* __restrict__ yp,
                     float* __restrict__ out) {
  const int lane = threadIdx.x;          // lane i covers x = 2i, 2i+1 (full row)
  const int ty   = threadIdx.y;          // row within block (0..3); wave id
  const int tid  = ty * TX + lane;

  const int yy = blockIdx.x * TY + ty;   // global row 0..127 (wave-uniform)
  const int z0 = blockIdx.y * ZC;
  const int b  = blockIdx.z;

  const v2f* Y0 = (const v2f*)y  + (size_t)b * 2 * CS2;   // vol y, ch 0
  const v2f* Y1 = Y0 + CS2;                               // vol y, ch 1
  const v2f* P0 = (const v2f*)yp + (size_t)b * 2 * CS2;   // vol yp, ch 0
  const v2f* P1 = P0 + CS2;

  // y-clamped row bases (wave-uniform) + value masks for clamped rows
  const int yM = yy > 0 ? yy - 1 : 0;
  const int yP = yy < YDIM - 1 ? yy + 1 : YDIM - 1;
  const int oM = yM * XW + lane;
  const int oC = yy * XW + lane;
  const int oP = yP * XW + lane;
  const float mm = (yy > 0) ? 1.0f : 0.0f;
  const float mp = (yy < YDIM - 1) ? 1.0f : 0.0f;

  // seam exchange: prev lane's x1 (.y), next lane's x0 (.x); volume-edge zeros
  const int addrL = (lane > 0 ? lane - 1 : 0) << 2;
  const int addrR = (lane < TX - 1 ? lane + 1 : TX - 1) << 2;
  const float lz = (lane == 0) ? 0.0f : 1.0f;
  const float rz = (lane == TX - 1) ? 0.0f : 1.0f;

  // RAW ring (2 planes in flight): [0..3]=rows y-1 (Y0,Y1,P0,P1),
  // [4..7]=row y, [8..11]=row y+1.
  v2f pf[2][12];
  // channel-summed row history, mod-3 planes: [0..2]=Y rows m,c,p; [3..5]=P.
  v2f R[3][6];
  v2f accv = {0.0f, 0.0f};

  auto loadRaw = [&](int buf, int zc) {
    const int zca = zc < 0 ? 0 : (zc > ZDIM - 1 ? ZDIM - 1 : zc);
    const int o   = zca * YX2;
    pf[buf][0]  = Y0[o + oM]; pf[buf][1]  = Y1[o + oM];
    pf[buf][2]  = P0[o + oM]; pf[buf][3]  = P1[o + oM];
    pf[buf][4]  = Y0[o + oC]; pf[buf][5]  = Y1[o + oC];
    pf[buf][6]  = P0[o + oC]; pf[buf][7]  = P1[o + oC];
    pf[buf][8]  = Y0[o + oP]; pf[buf][9]  = Y1[o + oP];
    pf[buf][10] = P0[o + oP]; pf[buf][11] = P1[o + oP];
  };

  // channel-sum raw plane into history slot, applying y/z value masks
  auto sumPlane = [&](int rs, int buf, float fz) {
    const v2f* q = pf[buf];
    R[rs][0] = (q[0] + q[1])   * vsplat(fz * mm);
    R[rs][3] = (q[2] + q[3])   * vsplat(fz * mm);
    R[rs][1] = (q[4] + q[5])   * vsplat(fz);
    R[rs][4] = (q[6] + q[7])   * vsplat(fz);
    R[rs][2] = (q[8] + q[9])   * vsplat(fz * mp);
    R[rs][5] = (q[10] + q[11]) * vsplat(fz * mp);
  };

  // full z->y->x combine + sum of 9 squared gradients for one volume
  auto volSS = [&](const v2f* za, const v2f* zb, const v2f* zc2) -> v2f {
    const v2f two = vsplat(2.0f);
    v2f zs[3], zd[3], ze[3];
#pragma unroll
    for (int r = 0; r < 3; ++r) {
      const v2f t = za[r] + zc2[r];
      zs[r] = vfma(two, zb[r], t);
      zd[r] = zc2[r] - za[r];
      ze[r] = t + zb[r];
    }
    const v2f t1 = zs[0] + zs[2];
    const v2f ss = vfma(two, zs[1], t1);
    const v2f sd = zs[2] - zs[0];
    const v2f se = t1 + zs[1];
    const v2f t2 = zd[0] + zd[2];
    const v2f ds = vfma(two, zd[1], t2);
    const v2f de = t2 + zd[1];
    const v2f t3 = ze[0] + ze[2];
    const v2f es = vfma(two, ze[1], t3);
    const v2f ed = ze[2] - ze[0];

    auto DX = [&](v2f q) -> v2f {             // d_x
      const float l  = bperm(addrL, q.y) * lz;
      const float r2 = bperm(addrR, q.x) * rz;
      v2f o; o.x = q.y - l; o.y = r2 - q.x; return o;
    };
    auto SX = [&](v2f q) -> v2f {             // s_x
      const float l  = bperm(addrL, q.y) * lz;
      const float r2 = bperm(addrR, q.x) * rz;
      v2f t; t.x = l + q.y; t.y = q.x + r2;
      return vfma(two, q, t);
    };
    auto SXEX = [&](v2f q, v2f& ex) -> v2f {  // s_x and e_x
      const float l  = bperm(addrL, q.y) * lz;
      const float r2 = bperm(addrR, q.x) * rz;
      v2f t; t.x = l + q.y; t.y = q.x + r2;
      ex = t + q;
      return vfma(two, q, t);
    };

    const v2f g1 = DX(ss);
    v2f ex_sd;  const v2f g2 = SXEX(sd, ex_sd);
    v2f ex_ds;  const v2f g3 = SXEX(ds, ex_ds);
    const v2f dxse = DX(se);
    const v2f sxde = SX(de);
    const v2f sxed = SX(ed);
    const v2f dxes = DX(es);
    const v2f g4 = dxse - ex_sd, g5 = dxse + ex_sd;   // Sd11, Sd12
    const v2f g6 = sxde - sxed, g7 = sxde + sxed;     // Sd21, Sd22
    const v2f g8 = dxes - ex_ds, g9 = dxes + ex_ds;   // Sd31, Sd32

    v2f s = vfma(g1, g1, vsplat(1e-12f));
    s = vfma(g2, g2, s); s = vfma(g3, g3, s);
    s = vfma(g4, g4, s); s = vfma(g5, g5, s);
    s = vfma(g6, g6, s); s = vfma(g7, g7, s);
    s = vfma(g8, g8, s); s = vfma(g9, g9, s);
    return s;
  };

  // prologue: raw planes j=0 (zc=z0-1) and j=1 (zc=z0) into ring slots 0,1
  loadRaw(0, z0 - 1);
  loadRaw(1, z0);

#pragma unroll
  for (int j = 0; j < ZC + 2; ++j) {            // 10 planes, zc = z0-1+j
    // (a) channel-sum plane j (raw issued at iter j-2 => 2-iteration cover)
    const int   zc = z0 - 1 + j;
    const float fz = ((unsigned)zc < (unsigned)ZDIM) ? 1.0f : 0.0f;
    sumPlane(j % 3, j % 2, fz);
    // (b) reuse the ring slot: issue raw plane j+2 (z-clamped, branchless)
    loadRaw(j % 2, z0 + 1 + j);
    // (c) emit output plane z0+j-2 from history planes j-2, j-1, j
    if (j >= 2) {
      const v2f* Ra = R[(j - 2) % 3];
      const v2f* Rb = R[(j - 1) % 3];
      const v2f* Rc = R[j % 3];
      const v2f ssY = volSS(Ra + 0, Rb + 0, Rc + 0);
      const v2f ssP = volSS(Ra + 3, Rb + 3, Rc + 3);
      v2f d;
      d.x = 0.5f * (__builtin_amdgcn_sqrtf(ssY.x) - __builtin_amdgcn_sqrtf(ssP.x));
      d.y = 0.5f * (__builtin_amdgcn_sqrtf(ssY.y) - __builtin_amdgcn_sqrtf(ssP.y));
      accv = vfma(d, d, accv);
    }
  }

  // ---- block reduction (only sync in the kernel) ----
  __shared__ float red[4];
  float acc = accv.x + accv.y;
#pragma unroll
  for (int off = 32; off > 0; off >>= 1) acc += __shfl_down(acc, off);
  if (lane == 0) red[ty] = acc;                 // wave id == ty (TX==64)
  __syncthreads();
  if (tid == 0) {
    const float s = (red[0] + red[1] + red[2] + red[3]) * INV_N;
    atomicAdd(out, s);
  }
}

}  // namespace

extern "C" void kernel_launch(void* const* d_in, const int* in_sizes, int n_in,
                              void* d_out, int out_size, void* d_ws, size_t ws_size,
                              hipStream_t stream) {
  const float* y  = (const float*)d_in[0];
  const float* yp = (const float*)d_in[1];
  float* out = (float*)d_out;

  // d_out is poisoned before every launch: zero via memset node (graph-capturable)
  hipMemsetAsync(out, 0, sizeof(float), stream);

  dim3 block(TX, TY, 1);                        // 256 threads = 4 full-row waves
  dim3 grid(YDIM / TY,                          // 32 y-tiles
            ZDIM / ZC,                          // 16 z-chunks
            2);                                 // batch  => 1024 blocks, 4/CU
  gme_loss_kernel<<<grid, block, 0, stream>>>(y, yp, out);
}

// Round 12
// 116.552 us; speedup vs baseline: 1.4426x; 1.4426x over previous
//
#include <hip/hip_runtime.h>

// GMELoss3D: fused 3D Sobel edge-magnitude MSE on [2,2,128,128,128] fp32 volumes.
// R14: R13's factorized algorithm, NATURAL register allocation (no clamp).
//   - R13 post-mortem: launch_bounds(256,4) didn't cap at 128 — allocator
//     overshot to 64 VGPR and paid 131MB scratch writes -> 93us. Twice-paid
//     lesson (R3, R13): min-waves clamps overshoot to the next occupancy tier
//     and spill. NEVER clamp on this compiler.
//   - The r-history factorization itself PASSED (absmax 0.0) and needs only
//     ~84 persistent floats vs R12's ~128: per-row channel-sums R (3 rows x
//     2 vols x mod-3 z-history = 36 floats) + ring-2 raw (48 floats); full
//     z->y->x combine at emit. Natural allocation should land ~120-150 VGPR
//     => 3-4 waves/SIMD vs R12's 2, no spill risk.
//   - ZC=8: 1024 blocks = 4/CU supply for up to 16 waves/CU residency.
//   - Ring-2 slot reuse keeps 2-iteration vmcnt cover: iter j sums plane j
//     (issued at j-2), then reissues the slot for plane j+2.
//   - Kept: branchless clamped loads, consume-time value masks, full-row
//     waves with dwordx2, seam bperms, v_sqrt_f32, no __syncthreads in the
//     z-loop, full unroll (10 iters; all indices static, rule #20).
//
// Decomposition: s=[1,2,1], d=[-1,0,1], e=[1,1,1] applied z-first at emit:
//   per row: zs,zd,ze; y-combine to 7 (z,y) pairs ss,sd,ds,se,de,ed,es;
//   x-combine: g1=dx(ss) g2=sx(sd) g3=sx(ds) g4/5=dx(se)∓ex(sd)
//   g6/7=sx(de)∓sx(ed) g8/9=dx(es)∓ex(ds). Signs irrelevant (squared).

namespace {

typedef float v2f __attribute__((ext_vector_type(2)));

constexpr int ZDIM = 128, YDIM = 128, XDIM = 128;   // (H, W, D); D contiguous
constexpr int TX = 64, TY = 4, ZC = 8;
constexpr int XW  = XDIM / 2;             // 64 float2 per row (lane i: x=2i,2i+1)
constexpr int YX2 = YDIM * XW;            // float2 per z-plane
constexpr size_t CS2 = (size_t)ZDIM * YX2;  // channel stride in float2
constexpr float INV_N = 1.0f / 4194304.0f;

__device__ __forceinline__ float bperm(int addr, float v) {
  return __int_as_float(__builtin_amdgcn_ds_bpermute(addr, __float_as_int(v)));
}

__device__ __forceinline__ v2f vfma(v2f a, v2f b, v2f c) {
  return __builtin_elementwise_fma(a, b, c);
}

__device__ __forceinline__ v2f vsplat(float x) { v2f r = {x, x}; return r; }

__global__ __launch_bounds__(256)       // natural allocation — NO waves clamp
void gme_loss_kernel(const float* __restrict__ y,
                     const float* __restrict__ yp,
                     float* __restrict__ out) {
  const int lane = threadIdx.x;          // lane i covers x = 2i, 2i+1 (full row)
  const int ty   = threadIdx.y;          // row within block (0..3); wave id
  const int tid  = ty * TX + lane;

  const int yy = blockIdx.x * TY + ty;   // global row 0..127 (wave-uniform)
  const int z0 = blockIdx.y * ZC;
  const int b  = blockIdx.z;

  const v2f* Y0 = (const v2f*)y  + (size_t)b * 2 * CS2;   // vol y, ch 0
  const v2f* Y1 = Y0 + CS2;                               // vol y, ch 1
  const v2f* P0 = (const v2f*)yp + (size_t)b * 2 * CS2;   // vol yp, ch 0
  const v2f* P1 = P0 + CS2;

  // y-clamped row bases (wave-uniform) + value masks for clamped rows
  const int yM = yy > 0 ? yy - 1 : 0;
  const int yP = yy < YDIM - 1 ? yy + 1 : YDIM - 1;
  const int oM = yM * XW + lane;
  const int oC = yy * XW + lane;
  const int oP = yP * XW + lane;
  const float mm = (yy > 0) ? 1.0f : 0.0f;
  const float mp = (yy < YDIM - 1) ? 1.0f : 0.0f;

  // seam exchange: prev lane's x1 (.y), next lane's x0 (.x); volume-edge zeros
  const int addrL = (lane > 0 ? lane - 1 : 0) << 2;
  const int addrR = (lane < TX - 1 ? lane + 1 : TX - 1) << 2;
  const float lz = (lane == 0) ? 0.0f : 1.0f;
  const float rz = (lane == TX - 1) ? 0.0f : 1.0f;

  // RAW ring (2 planes in flight): [0..3]=rows y-1 (Y0,Y1,P0,P1),
  // [4..7]=row y, [8..11]=row y+1.
  v2f pf[2][12];
  // channel-summed row history, mod-3 planes: [0..2]=Y rows m,c,p; [3..5]=P.
  v2f R[3][6];
  v2f accv = {0.0f, 0.0f};

  auto loadRaw = [&](int buf, int zc) {
    const int zca = zc < 0 ? 0 : (zc > ZDIM - 1 ? ZDIM - 1 : zc);
    const int o   = zca * YX2;
    pf[buf][0]  = Y0[o + oM]; pf[buf][1]  = Y1[o + oM];
    pf[buf][2]  = P0[o + oM]; pf[buf][3]  = P1[o + oM];
    pf[buf][4]  = Y0[o + oC]; pf[buf][5]  = Y1[o + oC];
    pf[buf][6]  = P0[o + oC]; pf[buf][7]  = P1[o + oC];
    pf[buf][8]  = Y0[o + oP]; pf[buf][9]  = Y1[o + oP];
    pf[buf][10] = P0[o + oP]; pf[buf][11] = P1[o + oP];
  };

  // channel-sum raw plane into history slot, applying y/z value masks
  auto sumPlane = [&](int rs, int buf, float fz) {
    const v2f* q = pf[buf];
    R[rs][0] = (q[0] + q[1])   * vsplat(fz * mm);
    R[rs][3] = (q[2] + q[3])   * vsplat(fz * mm);
    R[rs][1] = (q[4] + q[5])   * vsplat(fz);
    R[rs][4] = (q[6] + q[7])   * vsplat(fz);
    R[rs][2] = (q[8] + q[9])   * vsplat(fz * mp);
    R[rs][5] = (q[10] + q[11]) * vsplat(fz * mp);
  };

  // full z->y->x combine + sum of 9 squared gradients for one volume
  auto volSS = [&](const v2f* za, const v2f* zb, const v2f* zc2) -> v2f {
    const v2f two = vsplat(2.0f);
    v2f zs[3], zd[3], ze[3];
#pragma unroll
    for (int r = 0; r < 3; ++r) {
      const v2f t = za[r] + zc2[r];
      zs[r] = vfma(two, zb[r], t);
      zd[r] = zc2[r] - za[r];
      ze[r] = t + zb[r];
    }
    const v2f t1 = zs[0] + zs[2];
    const v2f ss = vfma(two, zs[1], t1);
    const v2f sd = zs[2] - zs[0];
    const v2f se = t1 + zs[1];
    const v2f t2 = zd[0] + zd[2];
    const v2f ds = vfma(two, zd[1], t2);
    const v2f de = t2 + zd[1];
    const v2f t3 = ze[0] + ze[2];
    const v2f es = vfma(two, ze[1], t3);
    const v2f ed = ze[2] - ze[0];

    auto DX = [&](v2f q) -> v2f {             // d_x
      const float l  = bperm(addrL, q.y) * lz;
      const float r2 = bperm(addrR, q.x) * rz;
      v2f o; o.x = q.y - l; o.y = r2 - q.x; return o;
    };
    auto SX = [&](v2f q) -> v2f {             // s_x
      const float l  = bperm(addrL, q.y) * lz;
      const float r2 = bperm(addrR, q.x) * rz;
      v2f t; t.x = l + q.y; t.y = q.x + r2;
      return vfma(two, q, t);
    };
    auto SXEX = [&](v2f q, v2f& ex) -> v2f {  // s_x and e_x
      const float l  = bperm(addrL, q.y) * lz;
      const float r2 = bperm(addrR, q.x) * rz;
      v2f t; t.x = l + q.y; t.y = q.x + r2;
      ex = t + q;
      return vfma(two, q, t);
    };

    const v2f g1 = DX(ss);
    v2f ex_sd;  const v2f g2 = SXEX(sd, ex_sd);
    v2f ex_ds;  const v2f g3 = SXEX(ds, ex_ds);
    const v2f dxse = DX(se);
    const v2f sxde = SX(de);
    const v2f sxed = SX(ed);
    const v2f dxes = DX(es);
    const v2f g4 = dxse - ex_sd, g5 = dxse + ex_sd;   // Sd11, Sd12
    const v2f g6 = sxde - sxed, g7 = sxde + sxed;     // Sd21, Sd22
    const v2f g8 = dxes - ex_ds, g9 = dxes + ex_ds;   // Sd31, Sd32

    v2f s = vfma(g1, g1, vsplat(1e-12f));
    s = vfma(g2, g2, s); s = vfma(g3, g3, s);
    s = vfma(g4, g4, s); s = vfma(g5, g5, s);
    s = vfma(g6, g6, s); s = vfma(g7, g7, s);
    s = vfma(g8, g8, s); s = vfma(g9, g9, s);
    return s;
  };

  // prologue: raw planes j=0 (zc=z0-1) and j=1 (zc=z0) into ring slots 0,1
  loadRaw(0, z0 - 1);
  loadRaw(1, z0);

#pragma unroll
  for (int j = 0; j < ZC + 2; ++j) {            // 10 planes, zc = z0-1+j
    // (a) channel-sum plane j (raw issued at iter j-2 => 2-iteration cover)
    const int   zc = z0 - 1 + j;
    const float fz = ((unsigned)zc < (unsigned)ZDIM) ? 1.0f : 0.0f;
    sumPlane(j % 3, j % 2, fz);
    // (b) reuse the ring slot: issue raw plane j+2 (z-clamped, branchless)
    loadRaw(j % 2, z0 + 1 + j);
    // (c) emit output plane z0+j-2 from history planes j-2, j-1, j
    if (j >= 2) {
      const v2f* Ra = R[(j - 2) % 3];
      const v2f* Rb = R[(j - 1) % 3];
      const v2f* Rc = R[j % 3];
      const v2f ssY = volSS(Ra + 0, Rb + 0, Rc + 0);
      const v2f ssP = volSS(Ra + 3, Rb + 3, Rc + 3);
      v2f d;
      d.x = 0.5f * (__builtin_amdgcn_sqrtf(ssY.x) - __builtin_amdgcn_sqrtf(ssP.x));
      d.y = 0.5f * (__builtin_amdgcn_sqrtf(ssY.y) - __builtin_amdgcn_sqrtf(ssP.y));
      accv = vfma(d, d, accv);
    }
  }

  // ---- block reduction (only sync in the kernel) ----
  __shared__ float red[4];
  float acc = accv.x + accv.y;
#pragma unroll
  for (int off = 32; off > 0; off >>= 1) acc += __shfl_down(acc, off);
  if (lane == 0) red[ty] = acc;                 // wave id == ty (TX==64)
  __syncthreads();
  if (tid == 0) {
    const float s = (red[0] + red[1] + red[2] + red[3]) * INV_N;
    atomicAdd(out, s);
  }
}

}  // namespace

extern "C" void kernel_launch(void* const* d_in, const int* in_sizes, int n_in,
                              void* d_out, int out_size, void* d_ws, size_t ws_size,
                              hipStream_t stream) {
  const float* y  = (const float*)d_in[0];
  const float* yp = (const float*)d_in[1];
  float* out = (float*)d_out;

  // d_out is poisoned before every launch: zero via memset node (graph-capturable)
  hipMemsetAsync(out, 0, sizeof(float), stream);

  dim3 block(TX, TY, 1);                        // 256 threads = 4 full-row waves
  dim3 grid(YDIM / TY,                          // 32 y-tiles
            ZDIM / ZC,                          // 16 z-chunks
            2);                                 // batch  => 1024 blocks, 4/CU
  gme_loss_kernel<<<grid, block, 0, stream>>>(y, yp, out);
}

// Round 13
// 107.101 us; speedup vs baseline: 1.5699x; 1.0882x over previous
//
#include <hip/hip_runtime.h>

// GMELoss3D: fused 3D Sobel edge-magnitude MSE on [2,2,128,128,128] fp32 volumes.
// R15: R12 base + INLINE-ASM loads with explicit counted s_waitcnt vmcnt(24).
//   - R14 post-mortem: factorization regressed (~40us vs R12's ~31; emit-time
//     bperm clump doubled DS ops). R13/R14 kill the occupancy lever from both
//     sides. Across ALL non-spilling rounds waves are 70-85% stalled with no
//     pipe saturated => vmcnt waits. The "counted vmcnt" I assumed in
//     R10/R11/R12 was never verified; hipcc defeats source-level pipelining
//     for ITS loads. Fix: take the loads away from the compiler.
//   - 12 loads/plane as asm volatile global_load_dwordx2 (SGPR-pair bases
//     Y0/Y1/P0/P1 + 3 per-lane VGPR byte offsets). Compiler doesn't track
//     them -> no conservative waits. At consume: ONE asm s_waitcnt vmcnt(24)
//     with the 12 consumed v2f as tied "+v" operands (pins consumers after
//     the wait; rule-#18 mitigation) + sched_barrier(0). Ring-3 => exactly
//     36 outstanding at the wait; oldest 12 (plane j) guaranteed landed;
//     2 full iterations of REAL latency cover. Drain vmcnt(0) after loop.
//   - CORRECTNESS TRIPWIRE: compiler scratch ops inside the loop would bump
//     vmcnt and corrupt the count -> passed:false or WRITE_SIZE in MBs ->
//     revert to R12. (R12 allocated ~180 VGPR with no spills; same budget.)
//   - Everything else IS R12: full-row waves, dwordx2, ZC=16, 512 co-resident
//     blocks, branchless clamped addressing, consume-time masks, seam
//     bperms, mod-2 K pipeline + end-of-iter shift, unroll 6, v_sqrt_f32,
//     no __syncthreads in the z-loop, NO launch_bounds waves clamp (R3/R13).
//
// Decomposition: s=[1,2,1], d=[-1,0,1], e=[1,1,1], y-first per plane:
//   C0=s_y d_x  C1=d_y s_x  C2=s_y s_x  C3=e_y d_x  C4=d_y e_x  C5=e_y s_x
//   C6=s_y e_x ; z-combines in emag_ss. Signs irrelevant (squared).

namespace {

typedef float v2f __attribute__((ext_vector_type(2)));

constexpr int ZDIM = 128, YDIM = 128, XDIM = 128;   // (H, W, D); D contiguous
constexpr int TX = 64, TY = 4, ZC = 16;
constexpr int XW  = XDIM / 2;             // 64 float2 per row (lane i: x=2i,2i+1)
constexpr int YX2 = YDIM * XW;            // float2 per z-plane
constexpr size_t CS2 = (size_t)ZDIM * YX2;  // channel stride in float2
constexpr float INV_N = 1.0f / 4194304.0f;

__device__ __forceinline__ float bperm(int addr, float v) {
  return __int_as_float(__builtin_amdgcn_ds_bpermute(addr, __float_as_int(v)));
}

__device__ __forceinline__ v2f vfma(v2f a, v2f b, v2f c) {
  return __builtin_elementwise_fma(a, b, c);
}

__device__ __forceinline__ v2f vsplat(float x) { v2f r = {x, x}; return r; }

// packed (over 2 x-columns) sum-of-squares of the 9 gradients (+eps)
__device__ __forceinline__ v2f emag_ss(const v2f* __restrict__ Ca,
                                       const v2f* __restrict__ Cb,
                                       const v2f* __restrict__ Cc) {
  const v2f two = vsplat(2.0f);
  const v2f g1  = vfma(two, Cb[0], Ca[0] + Cc[0]);   // Sx
  const v2f g2  = vfma(two, Cb[1], Ca[1] + Cc[1]);   // Sy
  const v2f g3  = Cc[2] - Ca[2];                     // Sz
  const v2f Azx = vfma(two, Cb[3], Ca[3] + Cc[3]);   // s_z e_y d_x
  const v2f Azy = vfma(two, Cb[4], Ca[4] + Cc[4]);   // s_z d_y e_x
  const v2f Axz = Cc[5] - Ca[5];                     // d_z e_y s_x
  const v2f Axy = g2 - Cb[1];                        // e_z d_y s_x
  const v2f Ayx = g1 - Cb[0];                        // e_z s_y d_x
  const v2f Ayz = Cc[6] - Ca[6];                     // d_z s_y e_x
  const v2f g4 = Azx - Azy, g5 = Azx + Azy;          // Sd11, Sd12
  const v2f g6 = Axz - Axy, g7 = Axz + Axy;          // Sd21, Sd22
  const v2f g8 = Ayx - Ayz, g9 = Ayx + Ayz;          // Sd31, Sd32
  v2f s = vfma(g1, g1, vsplat(1e-12f));
  s = vfma(g2, g2, s); s = vfma(g3, g3, s);
  s = vfma(g4, g4, s); s = vfma(g5, g5, s);
  s = vfma(g6, g6, s); s = vfma(g7, g7, s);
  s = vfma(g8, g8, s); s = vfma(g9, g9, s);
  return s;
}

__global__ __launch_bounds__(256)       // natural allocation — NO waves clamp
void gme_loss_kernel(const float* __restrict__ y,
                     const float* __restrict__ yp,
                     float* __restrict__ out) {
  const int lane = threadIdx.x;          // lane i covers x = 2i, 2i+1 (full row)
  const int ty   = threadIdx.y;          // row within block (0..3); wave id
  const int tid  = ty * TX + lane;

  const int yy = blockIdx.x * TY + ty;   // global row 0..127 (wave-uniform)
  const int z0 = blockIdx.y * ZC;
  const int b  = blockIdx.z;

  const v2f* Y0 = (const v2f*)y  + (size_t)b * 2 * CS2;   // vol y, ch 0
  const v2f* Y1 = Y0 + CS2;                               // vol y, ch 1
  const v2f* P0 = (const v2f*)yp + (size_t)b * 2 * CS2;   // vol yp, ch 0
  const v2f* P1 = P0 + CS2;

  // y-clamped row bases (wave-uniform) + value masks for clamped rows
  const int yM = yy > 0 ? yy - 1 : 0;
  const int yP = yy < YDIM - 1 ? yy + 1 : YDIM - 1;
  const int oM8 = (yM * XW + lane) * 8;  // byte offsets for dwordx2
  const int oC8 = (yy * XW + lane) * 8;
  const int oP8 = (yP * XW + lane) * 8;
  const float mm = (yy > 0) ? 1.0f : 0.0f;
  const float mp = (yy < YDIM - 1) ? 1.0f : 0.0f;

  // seam exchange: prev lane's x1 (.y), next lane's x0 (.x); volume-edge zeros
  const int addrL = (lane > 0 ? lane - 1 : 0) << 2;
  const int addrR = (lane < TX - 1 ? lane + 1 : TX - 1) << 2;
  const float lz = (lane == 0) ? 0.0f : 1.0f;
  const float rz = (lane == TX - 1) ? 0.0f : 1.0f;

  // RAW ring, 3 planes in flight (compiler-invisible asm loads).
  // [0]Y0m [1]Y1m [2]P0m [3]P1m [4]Y0c [5]Y1c [6]P0c [7]P1c [8]Y0p [9]Y1p [10]P0p [11]P1p
  v2f pf[3][12];
  v2f KY[2][7], KP[2][7];                // mod-2 combo pipeline (j-2, j-1)
  v2f accv = {0.0f, 0.0f};

  // 12 asm loads; volatile keeps issue order => vmcnt counts are exact.
  auto asmLoad = [&](v2f* d, int zc) {
    const int zca  = zc < 0 ? 0 : (zc > ZDIM - 1 ? ZDIM - 1 : zc);
    const int zoff = zca * (YX2 * 8);
    const int om = zoff + oM8, oc = zoff + oC8, op = zoff + oP8;
    asm volatile("global_load_dwordx2 %0, %1, %2" : "=v"(d[0])  : "v"(om), "s"(Y0));
    asm volatile("global_load_dwordx2 %0, %1, %2" : "=v"(d[1])  : "v"(om), "s"(Y1));
    asm volatile("global_load_dwordx2 %0, %1, %2" : "=v"(d[2])  : "v"(om), "s"(P0));
    asm volatile("global_load_dwordx2 %0, %1, %2" : "=v"(d[3])  : "v"(om), "s"(P1));
    asm volatile("global_load_dwordx2 %0, %1, %2" : "=v"(d[4])  : "v"(oc), "s"(Y0));
    asm volatile("global_load_dwordx2 %0, %1, %2" : "=v"(d[5])  : "v"(oc), "s"(Y1));
    asm volatile("global_load_dwordx2 %0, %1, %2" : "=v"(d[6])  : "v"(oc), "s"(P0));
    asm volatile("global_load_dwordx2 %0, %1, %2" : "=v"(d[7])  : "v"(oc), "s"(P1));
    asm volatile("global_load_dwordx2 %0, %1, %2" : "=v"(d[8])  : "v"(op), "s"(Y0));
    asm volatile("global_load_dwordx2 %0, %1, %2" : "=v"(d[9])  : "v"(op), "s"(Y1));
    asm volatile("global_load_dwordx2 %0, %1, %2" : "=v"(d[10]) : "v"(op), "s"(P0));
    asm volatile("global_load_dwordx2 %0, %1, %2" : "=v"(d[11]) : "v"(op), "s"(P1));
  };

  // x-combine: from quantity q (v2f over x) build the 7 per-plane combos
  auto combos = [&](v2f ys, v2f yd, v2f ye, v2f* __restrict__ C) {
    const float ysl = bperm(addrL, ys.y) * lz, ysr = bperm(addrR, ys.x) * rz;
    const float ydl = bperm(addrL, yd.y) * lz, ydr = bperm(addrR, yd.x) * rz;
    const float yel = bperm(addrL, ye.y) * lz, yer = bperm(addrR, ye.x) * rz;
    const v2f ysL = {ysl, ys.x}, ysR = {ys.y, ysr};
    const v2f ydL = {ydl, yd.x}, ydR = {yd.y, ydr};
    const v2f yeL = {yel, ye.x}, yeR = {ye.y, yer};
    const v2f tS = ysL + ysR, tD = ydL + ydR, tE = yeL + yeR;
    C[0] = ysR - ysL;                           // s_y d_x
    C[2] = vfma(vsplat(2.0f), ys, tS);          // s_y s_x
    C[6] = tS + ys;                             // s_y e_x
    C[1] = vfma(vsplat(2.0f), yd, tD);          // d_y s_x
    C[4] = tD + yd;                             // d_y e_x
    C[3] = yeR - yeL;                           // e_y d_x
    C[5] = vfma(vsplat(2.0f), ye, tE);          // e_y s_x
  };

  // prologue: planes j=0 (zc=z0-1), j=1 (zc=z0) -> ring slots 0,1 (24 in flight)
  asmLoad(pf[0], z0 - 1);
  asmLoad(pf[1], z0);

#pragma unroll 6
  for (int j = 0; j < ZC + 2; ++j) {            // 18 planes, zc = z0-1+j
    asmLoad(pf[(j + 2) % 3], z0 + 1 + j);       // issue plane j+2 -> 36 in flight

    // counted wait: oldest 12 (plane j, issued 2 iters ago) have landed.
    v2f* q = pf[j % 3];
    asm volatile("s_waitcnt vmcnt(24)"
                 : "+v"(q[0]), "+v"(q[1]), "+v"(q[2]), "+v"(q[3]),
                   "+v"(q[4]), "+v"(q[5]), "+v"(q[6]), "+v"(q[7]),
                   "+v"(q[8]), "+v"(q[9]), "+v"(q[10]), "+v"(q[11]));
    __builtin_amdgcn_sched_barrier(0);

    const int   zc = z0 - 1 + j;
    const float fz = ((unsigned)zc < (unsigned)ZDIM) ? 1.0f : 0.0f;
    const v2f smY = (q[0] + q[1])   * vsplat(fz * mm);   // ch-sums, masked
    const v2f smP = (q[2] + q[3])   * vsplat(fz * mm);
    const v2f scY = (q[4] + q[5])   * vsplat(fz);
    const v2f scP = (q[6] + q[7])   * vsplat(fz);
    const v2f spY = (q[8] + q[9])   * vsplat(fz * mp);
    const v2f spP = (q[10] + q[11]) * vsplat(fz * mp);

    v2f Cy[7], Cp[7];
    {
      const v2f tt = smY + spY;
      combos(vfma(vsplat(2.0f), scY, tt), spY - smY, tt + scY, Cy);
    }
    {
      const v2f tt = smP + spP;
      combos(vfma(vsplat(2.0f), scP, tt), spP - smP, tt + scP, Cp);
    }

    if (j >= 2) {                               // emit output plane z0+j-3
      const v2f ssY = emag_ss(KY[j % 2], KY[(j + 1) % 2], Cy);
      const v2f ssP = emag_ss(KP[j % 2], KP[(j + 1) % 2], Cp);
      v2f d;
      d.x = 0.5f * (__builtin_amdgcn_sqrtf(ssY.x) - __builtin_amdgcn_sqrtf(ssP.x));
      d.y = 0.5f * (__builtin_amdgcn_sqrtf(ssY.y) - __builtin_amdgcn_sqrtf(ssP.y));
      accv = vfma(d, d, accv);
    }

    // shift pipeline: slot j%2 (held plane j-2) now takes plane j
#pragma unroll
    for (int k = 0; k < 7; ++k) { KY[j % 2][k] = Cy[k]; KP[j % 2][k] = Cp[k]; }
  }

  // drain remaining in-flight loads before reduction / endpgm
  asm volatile("s_waitcnt vmcnt(0)");

  // ---- block reduction (only sync in the kernel) ----
  __shared__ float red[4];
  float acc = accv.x + accv.y;
#pragma unroll
  for (int off = 32; off > 0; off >>= 1) acc += __shfl_down(acc, off);
  if (lane == 0) red[ty] = acc;                 // wave id == ty (TX==64)
  __syncthreads();
  if (tid == 0) {
    const float s = (red[0] + red[1] + red[2] + red[3]) * INV_N;
    atomicAdd(out, s);
  }
}

}  // namespace

extern "C" void kernel_launch(void* const* d_in, const int* in_sizes, int n_in,
                              void* d_out, int out_size, void* d_ws, size_t ws_size,
                              hipStream_t stream) {
  const float* y  = (const float*)d_in[0];
  const float* yp = (const float*)d_in[1];
  float* out = (float*)d_out;

  // d_out is poisoned before every launch: zero via memset node (graph-capturable)
  hipMemsetAsync(out, 0, sizeof(float), stream);

  dim3 block(TX, TY, 1);                        // 256 threads = 4 full-row waves
  dim3 grid(YDIM / TY,                          // 32 y-tiles
            ZDIM / ZC,                          // 8 z-chunks
            2);                                 // batch  => 512 blocks, 2/CU
  gme_loss_kernel<<<grid, block, 0, stream>>>(y, yp, out);
}

// Round 14
// 105.910 us; speedup vs baseline: 1.5876x; 1.0113x over previous
//
#include <hip/hip_runtime.h>

// GMELoss3D: fused 3D Sobel edge-magnitude MSE on [2,2,128,128,128] fp32 volumes.
// R16: shrink the hot-loop body to ~3KB — test the INSTRUCTION-FETCH theory.
//   - R15 post-mortem: hand-counted vmcnt(24) with compiler-invisible loads =
//     NULL vs R12 (~32us both). Latency family fully exhausted (barriers,
//     ring depth, branchless, explicit waitcnt: all null). Still 2.5x above
//     the 12.7us fetch floor with no pipe saturated.
//   - Last untested mechanism that fits every null: I-CACHE / instruction
//     fetch. Every variant since R7 has a 10KB+ unrolled body (unroll 6 x
//     ~200 instr); a fetch-stalled loop is insensitive to occupancy, ring
//     depth, VALU count, and waitcnt placement — exactly the observed
//     invariance. R6 (largest body) was the slowest non-spill kernel.
//   - Changes vs R15 (two, both body-size-directed): ring 3->2 with
//     s_waitcnt vmcnt(12) (R10 proved ring-3 == ring-2 in time, so any delta
//     attributes to code size); #pragma unroll 2 (all %2 indices static,
//     rule #20; body ~400 instr ~3KB). Plane j+2 issued AFTER consuming
//     plane j (slot reuse); 2-iteration cover retained (plane j+1 issued at
//     iter j-1, consumed at j+1; wait vmcnt(12) guarantees oldest 12 landed).
//   - PRE-COMMITTED: if null, R12/R15 is the practical ceiling; declare next
//     round. Everything else frozen from R15: full-row waves, dwordx2 asm
//     loads, consume-time masks, seam bperms, mod-2 K pipeline, v_sqrt_f32,
//     512 co-resident blocks, no __syncthreads in z-loop, no waves clamp.
//
// Decomposition: s=[1,2,1], d=[-1,0,1], e=[1,1,1], y-first per plane:
//   C0=s_y d_x  C1=d_y s_x  C2=s_y s_x  C3=e_y d_x  C4=d_y e_x  C5=e_y s_x
//   C6=s_y e_x ; z-combines in emag_ss. Signs irrelevant (squared).

namespace {

typedef float v2f __attribute__((ext_vector_type(2)));

constexpr int ZDIM = 128, YDIM = 128, XDIM = 128;   // (H, W, D); D contiguous
constexpr int TX = 64, TY = 4, ZC = 16;
constexpr int XW  = XDIM / 2;             // 64 float2 per row (lane i: x=2i,2i+1)
constexpr int YX2 = YDIM * XW;            // float2 per z-plane
constexpr size_t CS2 = (size_t)ZDIM * YX2;  // channel stride in float2
constexpr float INV_N = 1.0f / 4194304.0f;

__device__ __forceinline__ float bperm(int addr, float v) {
  return __int_as_float(__builtin_amdgcn_ds_bpermute(addr, __float_as_int(v)));
}

__device__ __forceinline__ v2f vfma(v2f a, v2f b, v2f c) {
  return __builtin_elementwise_fma(a, b, c);
}

__device__ __forceinline__ v2f vsplat(float x) { v2f r = {x, x}; return r; }

// packed (over 2 x-columns) sum-of-squares of the 9 gradients (+eps)
__device__ __forceinline__ v2f emag_ss(const v2f* __restrict__ Ca,
                                       const v2f* __restrict__ Cb,
                                       const v2f* __restrict__ Cc) {
  const v2f two = vsplat(2.0f);
  const v2f g1  = vfma(two, Cb[0], Ca[0] + Cc[0]);   // Sx
  const v2f g2  = vfma(two, Cb[1], Ca[1] + Cc[1]);   // Sy
  const v2f g3  = Cc[2] - Ca[2];                     // Sz
  const v2f Azx = vfma(two, Cb[3], Ca[3] + Cc[3]);   // s_z e_y d_x
  const v2f Azy = vfma(two, Cb[4], Ca[4] + Cc[4]);   // s_z d_y e_x
  const v2f Axz = Cc[5] - Ca[5];                     // d_z e_y s_x
  const v2f Axy = g2 - Cb[1];                        // e_z d_y s_x
  const v2f Ayx = g1 - Cb[0];                        // e_z s_y d_x
  const v2f Ayz = Cc[6] - Ca[6];                     // d_z s_y e_x
  const v2f g4 = Azx - Azy, g5 = Azx + Azy;          // Sd11, Sd12
  const v2f g6 = Axz - Axy, g7 = Axz + Axy;          // Sd21, Sd22
  const v2f g8 = Ayx - Ayz, g9 = Ayx + Ayz;          // Sd31, Sd32
  v2f s = vfma(g1, g1, vsplat(1e-12f));
  s = vfma(g2, g2, s); s = vfma(g3, g3, s);
  s = vfma(g4, g4, s); s = vfma(g5, g5, s);
  s = vfma(g6, g6, s); s = vfma(g7, g7, s);
  s = vfma(g8, g8, s); s = vfma(g9, g9, s);
  return s;
}

__global__ __launch_bounds__(256)       // natural allocation — NO waves clamp
void gme_loss_kernel(const float* __restrict__ y,
                     const float* __restrict__ yp,
                     float* __restrict__ out) {
  const int lane = threadIdx.x;          // lane i covers x = 2i, 2i+1 (full row)
  const int ty   = threadIdx.y;          // row within block (0..3); wave id
  const int tid  = ty * TX + lane;

  const int yy = blockIdx.x * TY + ty;   // global row 0..127 (wave-uniform)
  const int z0 = blockIdx.y * ZC;
  const int b  = blockIdx.z;

  const v2f* Y0 = (const v2f*)y  + (size_t)b * 2 * CS2;   // vol y, ch 0
  const v2f* Y1 = Y0 + CS2;                               // vol y, ch 1
  const v2f* P0 = (const v2f*)yp + (size_t)b * 2 * CS2;   // vol yp, ch 0
  const v2f* P1 = P0 + CS2;

  // y-clamped row bases (wave-uniform) + value masks for clamped rows
  const int yM = yy > 0 ? yy - 1 : 0;
  const int yP = yy < YDIM - 1 ? yy + 1 : YDIM - 1;
  const int oM8 = (yM * XW + lane) * 8;  // byte offsets for dwordx2
  const int oC8 = (yy * XW + lane) * 8;
  const int oP8 = (yP * XW + lane) * 8;
  const float mm = (yy > 0) ? 1.0f : 0.0f;
  const float mp = (yy < YDIM - 1) ? 1.0f : 0.0f;

  // seam exchange: prev lane's x1 (.y), next lane's x0 (.x); volume-edge zeros
  const int addrL = (lane > 0 ? lane - 1 : 0) << 2;
  const int addrR = (lane < TX - 1 ? lane + 1 : TX - 1) << 2;
  const float lz = (lane == 0) ? 0.0f : 1.0f;
  const float rz = (lane == TX - 1) ? 0.0f : 1.0f;

  // RAW ring, 2 planes in flight (compiler-invisible asm loads).
  // [0]Y0m [1]Y1m [2]P0m [3]P1m [4]Y0c [5]Y1c [6]P0c [7]P1c [8]Y0p [9]Y1p [10]P0p [11]P1p
  v2f pf[2][12];
  v2f KY[2][7], KP[2][7];                // mod-2 combo pipeline (j-2, j-1)
  v2f accv = {0.0f, 0.0f};

  // 12 asm loads; volatile keeps issue order => vmcnt counts are exact.
  auto asmLoad = [&](v2f* d, int zc) {
    const int zca  = zc < 0 ? 0 : (zc > ZDIM - 1 ? ZDIM - 1 : zc);
    const int zoff = zca * (YX2 * 8);
    const int om = zoff + oM8, oc = zoff + oC8, op = zoff + oP8;
    asm volatile("global_load_dwordx2 %0, %1, %2" : "=v"(d[0])  : "v"(om), "s"(Y0));
    asm volatile("global_load_dwordx2 %0, %1, %2" : "=v"(d[1])  : "v"(om), "s"(Y1));
    asm volatile("global_load_dwordx2 %0, %1, %2" : "=v"(d[2])  : "v"(om), "s"(P0));
    asm volatile("global_load_dwordx2 %0, %1, %2" : "=v"(d[3])  : "v"(om), "s"(P1));
    asm volatile("global_load_dwordx2 %0, %1, %2" : "=v"(d[4])  : "v"(oc), "s"(Y0));
    asm volatile("global_load_dwordx2 %0, %1, %2" : "=v"(d[5])  : "v"(oc), "s"(Y1));
    asm volatile("global_load_dwordx2 %0, %1, %2" : "=v"(d[6])  : "v"(oc), "s"(P0));
    asm volatile("global_load_dwordx2 %0, %1, %2" : "=v"(d[7])  : "v"(oc), "s"(P1));
    asm volatile("global_load_dwordx2 %0, %1, %2" : "=v"(d[8])  : "v"(op), "s"(Y0));
    asm volatile("global_load_dwordx2 %0, %1, %2" : "=v"(d[9])  : "v"(op), "s"(Y1));
    asm volatile("global_load_dwordx2 %0, %1, %2" : "=v"(d[10]) : "v"(op), "s"(P0));
    asm volatile("global_load_dwordx2 %0, %1, %2" : "=v"(d[11]) : "v"(op), "s"(P1));
  };

  // x-combine: from quantity q (v2f over x) build the 7 per-plane combos
  auto combos = [&](v2f ys, v2f yd, v2f ye, v2f* __restrict__ C) {
    const float ysl = bperm(addrL, ys.y) * lz, ysr = bperm(addrR, ys.x) * rz;
    const float ydl = bperm(addrL, yd.y) * lz, ydr = bperm(addrR, yd.x) * rz;
    const float yel = bperm(addrL, ye.y) * lz, yer = bperm(addrR, ye.x) * rz;
    const v2f ysL = {ysl, ys.x}, ysR = {ys.y, ysr};
    const v2f ydL = {ydl, yd.x}, ydR = {yd.y, ydr};
    const v2f yeL = {yel, ye.x}, yeR = {ye.y, yer};
    const v2f tS = ysL + ysR, tD = ydL + ydR, tE = yeL + yeR;
    C[0] = ysR - ysL;                           // s_y d_x
    C[2] = vfma(vsplat(2.0f), ys, tS);          // s_y s_x
    C[6] = tS + ys;                             // s_y e_x
    C[1] = vfma(vsplat(2.0f), yd, tD);          // d_y s_x
    C[4] = tD + yd;                             // d_y e_x
    C[3] = yeR - yeL;                           // e_y d_x
    C[5] = vfma(vsplat(2.0f), ye, tE);          // e_y s_x
  };

  // prologue: planes j=0 (zc=z0-1) -> pf[0], j=1 (zc=z0) -> pf[1]; 24 in flight
  asmLoad(pf[0], z0 - 1);
  asmLoad(pf[1], z0);

#pragma unroll 2
  for (int j = 0; j < ZC + 2; ++j) {            // 18 planes, zc = z0-1+j
    // counted wait: oldest 12 (plane j, issued 2 iters ago) have landed;
    // plane j+1's 12 remain in flight.
    v2f* q = pf[j % 2];
    asm volatile("s_waitcnt vmcnt(12)"
                 : "+v"(q[0]), "+v"(q[1]), "+v"(q[2]), "+v"(q[3]),
                   "+v"(q[4]), "+v"(q[5]), "+v"(q[6]), "+v"(q[7]),
                   "+v"(q[8]), "+v"(q[9]), "+v"(q[10]), "+v"(q[11]));
    __builtin_amdgcn_sched_barrier(0);

    const int   zc = z0 - 1 + j;
    const float fz = ((unsigned)zc < (unsigned)ZDIM) ? 1.0f : 0.0f;
    const v2f smY = (q[0] + q[1])   * vsplat(fz * mm);   // ch-sums, masked
    const v2f smP = (q[2] + q[3])   * vsplat(fz * mm);
    const v2f scY = (q[4] + q[5])   * vsplat(fz);
    const v2f scP = (q[6] + q[7])   * vsplat(fz);
    const v2f spY = (q[8] + q[9])   * vsplat(fz * mp);
    const v2f spP = (q[10] + q[11]) * vsplat(fz * mp);

    // slot consumed -> reissue it with plane j+2 (WAR deps order this after
    // the ch-sum reads; 24 outstanding again after issue)
    asmLoad(q, z0 + 1 + j);

    v2f Cy[7], Cp[7];
    {
      const v2f tt = smY + spY;
      combos(vfma(vsplat(2.0f), scY, tt), spY - smY, tt + scY, Cy);
    }
    {
      const v2f tt = smP + spP;
      combos(vfma(vsplat(2.0f), scP, tt), spP - smP, tt + scP, Cp);
    }

    if (j >= 2) {                               // emit output plane z0+j-3
      const v2f ssY = emag_ss(KY[j % 2], KY[(j + 1) % 2], Cy);
      const v2f ssP = emag_ss(KP[j % 2], KP[(j + 1) % 2], Cp);
      v2f d;
      d.x = 0.5f * (__builtin_amdgcn_sqrtf(ssY.x) - __builtin_amdgcn_sqrtf(ssP.x));
      d.y = 0.5f * (__builtin_amdgcn_sqrtf(ssY.y) - __builtin_amdgcn_sqrtf(ssP.y));
      accv = vfma(d, d, accv);
    }

    // shift pipeline: slot j%2 (held plane j-2) now takes plane j
#pragma unroll
    for (int k = 0; k < 7; ++k) { KY[j % 2][k] = Cy[k]; KP[j % 2][k] = Cp[k]; }
  }

  // drain remaining in-flight loads before reduction / endpgm
  asm volatile("s_waitcnt vmcnt(0)");

  // ---- block reduction (only sync in the kernel) ----
  __shared__ float red[4];
  float acc = accv.x + accv.y;
#pragma unroll
  for (int off = 32; off > 0; off >>= 1) acc += __shfl_down(acc, off);
  if (lane == 0) red[ty] = acc;                 // wave id == ty (TX==64)
  __syncthreads();
  if (tid == 0) {
    const float s = (red[0] + red[1] + red[2] + red[3]) * INV_N;
    atomicAdd(out, s);
  }
}

}  // namespace

extern "C" void kernel_launch(void* const* d_in, const int* in_sizes, int n_in,
                              void* d_out, int out_size, void* d_ws, size_t ws_size,
                              hipStream_t stream) {
  const float* y  = (const float*)d_in[0];
  const float* yp = (const float*)d_in[1];
  float* out = (float*)d_out;

  // d_out is poisoned before every launch: zero via memset node (graph-capturable)
  hipMemsetAsync(out, 0, sizeof(float), stream);

  dim3 block(TX, TY, 1);                        // 256 threads = 4 full-row waves
  dim3 grid(YDIM / TY,                          // 32 y-tiles
            ZDIM / ZC,                          // 8 z-chunks
            2);                                 // batch  => 512 blocks, 2/CU
  gme_loss_kernel<<<grid, block, 0, stream>>>(y, yp, out);
}